// Round 4
// baseline (342.195 us; speedup 1.0000x reference)
//
#include <hip/hip_runtime.h>
#include <hip/hip_bf16.h>

#define QKVC   2304
#define NHEAD  12
#define NTOK   577
#define NBATCH 16
#define NROWS  (NBATCH * NTOK)   // 9232
#define NPAD   640
#define SCALE  0.125f
#define EPSV   1e-6f

typedef __bf16  bf16x8 __attribute__((ext_vector_type(8)));
typedef float   f32x4  __attribute__((ext_vector_type(4)));

__device__ __forceinline__ unsigned short f2bf(float f) {
    union { float f; unsigned u; } v; v.f = f;
    unsigned r = v.u + 0x7FFFu + ((v.u >> 16) & 1u);   // RNE
    return (unsigned short)(r >> 16);
}
__device__ __forceinline__ unsigned short f2bf_trunc(float f) {
    return (unsigned short)(__float_as_uint(f) >> 16);  // e>=0 only
}
__device__ __forceinline__ f32x4 mfma16(bf16x8 a, bf16x8 b, f32x4 c) {
    return __builtin_amdgcn_mfma_f32_16x16x32_bf16(a, b, c, 0, 0, 0);
}

// ---------------------------------------------------------------- x -> bf16
__global__ void k_convert_x(const float* __restrict__ x, unsigned short* __restrict__ xb) {
    int idx = blockIdx.x * 256 + threadIdx.x;
    float4 v = ((const float4*)x)[idx];
    ushort4 o;
    o.x = f2bf(v.x); o.y = f2bf(v.y); o.z = f2bf(v.z); o.w = f2bf(v.w);
    ((ushort4*)xb)[idx] = o;
}

// ------------------------------------------- W[K][N] fp32 -> Wt[N][K] bf16
__global__ void k_transpose_w(const float* __restrict__ src, unsigned short* __restrict__ dst,
                              int K, int N) {
    __shared__ unsigned short lt[64 * 72];
    int t  = threadIdx.x;
    int n0 = blockIdx.x * 64, k0 = blockIdx.y * 64;
    int kk = t >> 4, nn = (t & 15) * 4;
    for (int i = 0; i < 4; i++) {
        int kr = kk + i * 16;
        float4 v = *(const float4*)&src[(size_t)(k0 + kr) * N + n0 + nn];
        lt[(nn + 0) * 72 + kr] = f2bf(v.x);
        lt[(nn + 1) * 72 + kr] = f2bf(v.y);
        lt[(nn + 2) * 72 + kr] = f2bf(v.z);
        lt[(nn + 3) * 72 + kr] = f2bf(v.w);
    }
    __syncthreads();
    int n = t >> 2, seg = (t & 3) * 16;
    uint4 a = *(uint4*)&lt[n * 72 + seg];
    uint4 b = *(uint4*)&lt[n * 72 + seg + 8];
    *(uint4*)&dst[(size_t)(n0 + n) * K + k0 + seg]     = a;
    *(uint4*)&dst[(size_t)(n0 + n) * K + k0 + seg + 8] = b;
}

// -------------------------------------------------- 128x128 GEMM, K=768
// LDS-FREE, BARRIER-FREE: fragments load directly global->VGPR (L1/L2-served;
// each instr = 16 x 64B segments == same transaction count as contiguous 1KB).
// No syncthreads => no vmcnt(0) drains; compiler pipelines loads across iters;
// occupancy is VGPR-bound, not LDS-bound.
template <bool F32OUT>
__global__ __launch_bounds__(256, 4)
void k_gemm(const unsigned short* __restrict__ A, const unsigned short* __restrict__ B,
            const float* __restrict__ bias, void* __restrict__ outp, int Ncols) {
    int t = threadIdx.x;
    int lane = t & 63, wave = t >> 6, quad = lane >> 4, l15 = lane & 15;
    int wm = wave >> 1, wn = wave & 1;
    int m0 = blockIdx.x * 128, n0 = blockIdx.y * 128;

    const unsigned short* pa0 = A + (size_t)(m0 + wm * 64 +  0 + l15) * 768 + quad * 8;
    const unsigned short* pa1 = A + (size_t)(m0 + wm * 64 + 16 + l15) * 768 + quad * 8;
    const unsigned short* pa2 = A + (size_t)(m0 + wm * 64 + 32 + l15) * 768 + quad * 8;
    const unsigned short* pa3 = A + (size_t)(m0 + wm * 64 + 48 + l15) * 768 + quad * 8;
    const unsigned short* pb0 = B + (size_t)(n0 + wn * 64 +  0 + l15) * 768 + quad * 8;
    const unsigned short* pb1 = B + (size_t)(n0 + wn * 64 + 16 + l15) * 768 + quad * 8;
    const unsigned short* pb2 = B + (size_t)(n0 + wn * 64 + 32 + l15) * 768 + quad * 8;
    const unsigned short* pb3 = B + (size_t)(n0 + wn * 64 + 48 + l15) * 768 + quad * 8;

    f32x4 acc[4][4] = {};

    #pragma unroll 2
    for (int kt = 0; kt < 24; kt++) {
        int ko = kt * 32;
        bf16x8 af[4], bfr[4];
        af[0]  = *(const bf16x8*)(pa0 + ko);
        af[1]  = *(const bf16x8*)(pa1 + ko);
        af[2]  = *(const bf16x8*)(pa2 + ko);
        af[3]  = *(const bf16x8*)(pa3 + ko);
        bfr[0] = *(const bf16x8*)(pb0 + ko);
        bfr[1] = *(const bf16x8*)(pb1 + ko);
        bfr[2] = *(const bf16x8*)(pb2 + ko);
        bfr[3] = *(const bf16x8*)(pb3 + ko);
        for (int mi = 0; mi < 4; mi++)
            for (int ni = 0; ni < 4; ni++)
                acc[mi][ni] = mfma16(af[mi], bfr[ni], acc[mi][ni]);
    }

    for (int ni = 0; ni < 4; ni++) {
        int col = n0 + wn * 64 + ni * 16 + l15;
        float bv = bias[col];
        for (int mi = 0; mi < 4; mi++) {
            int rowm = m0 + wm * 64 + mi * 16 + quad * 4;
            for (int r = 0; r < 4; r++) {
                int m = rowm + r;
                if (m < NROWS) {
                    if constexpr (F32OUT)
                        ((float*)outp)[(size_t)m * Ncols + col] = acc[mi][ni][r] + bv;
                    else
                        ((unsigned short*)outp)[(size_t)m * Ncols + col] = f2bf(acc[mi][ni][r] + bv);
                }
            }
        }
    }
}

// -------------------------------------------- V slice of qkv -> V^T [d][tok]
__global__ void k_vtrans(const unsigned short* __restrict__ qkv, unsigned short* __restrict__ vt) {
    __shared__ unsigned short lt[64 * 72];
    int t = threadIdx.x;
    int b = blockIdx.z, h = blockIdx.y, tt = blockIdx.x;
    for (int i = t; i < 512; i += 256) {
        int row = i >> 3, seg = (i & 7) * 8;
        int tok = tt * 64 + row;
        uint4 v = {0, 0, 0, 0};
        if (tok < NTOK)
            v = *(const uint4*)&qkv[(size_t)(b * NTOK + tok) * QKVC + 1536 + h * 64 + seg];
        *(uint4*)&lt[row * 72 + seg] = v;
    }
    __syncthreads();
    for (int i = t; i < 512; i += 256) {
        int d = i >> 3, ts = i & 7;
        unsigned short tmp[8];
        for (int j = 0; j < 8; j++) tmp[j] = lt[(ts * 8 + j) * 72 + d];
        *(uint4*)&vt[((size_t)((b * NHEAD + h) * 64) + d) * NPAD + tt * 64 + ts * 8] =
            *(uint4*)tmp;
    }
}

// --------------------------------------------------------- flash attention
// 128 q-rows per block (2 m-tiles per wave): each staged K/V tile and each
// k-frag LDS read serves 2x rows. Q-frags load directly global->VGPR (no Qs).
// No max-subtraction (scores bounded); row-sum via ones-MFMA.
__global__ __launch_bounds__(256, 4)
void k_attn(const unsigned short* __restrict__ qkv, const unsigned short* __restrict__ vt,
            const float* __restrict__ policy, unsigned short* __restrict__ ao) {
    __shared__ unsigned short Ks[64 * 72];
    __shared__ unsigned short Vs[64 * 72];     // V^T tile [d][key]
    __shared__ unsigned short Ps[4][32 * 72];  // per-wave P tile [row][key]
    __shared__ float pol[NPAD];
    int t = threadIdx.x;
    int lane = t & 63, wave = t >> 6, quad = lane >> 4, l15 = lane & 15;
    int b = blockIdx.z, h = blockIdx.y, qt = blockIdx.x;
    const unsigned short* qbase = qkv + (size_t)(b * NTOK) * QKVC + h * 64;
    const unsigned short* kbase = qkv + (size_t)(b * NTOK) * QKVC + 768 + h * 64;
    const unsigned short* vbase = vt + (size_t)(b * NHEAD + h) * 64 * NPAD;

    for (int i = t; i < NPAD; i += 256)
        pol[i] = (i < NTOK) ? policy[b * NTOK + i] : 0.f;

    // Q fragments direct from global (rows beyond NTOK produce garbage rows
    // that are never stored; poison bytes decode to tiny bf16, no inf/NaN)
    bf16x8 qf[2][2];
    for (int mi = 0; mi < 2; mi++) {
        const unsigned short* qp =
            qbase + (size_t)(qt * 128 + mi * 64 + wave * 16 + l15) * QKVC + quad * 8;
        qf[mi][0] = *(const bf16x8*)qp;
        qf[mi][1] = *(const bf16x8*)(qp + 32);
    }
    bf16x8 onesf;
    for (int j = 0; j < 8; j++) onesf[j] = (__bf16)1.0f;
    f32x4 o[2][4] = {};
    f32x4 ls[2] = {};
    int rowtok0[2];
    for (int mi = 0; mi < 2; mi++)
        rowtok0[mi] = qt * 128 + mi * 64 + wave * 16 + quad * 4;
    __syncthreads();   // pol visible

    for (int kt = 0; kt < 10; kt++) {
        int key0 = kt * 64;
        for (int i = t; i < 512; i += 256) {
            int row = i >> 3, seg = (i & 7) * 8;
            *(uint4*)&Ks[row * 72 + seg] = *(const uint4*)&kbase[(size_t)(key0 + row) * QKVC + seg];
            *(uint4*)&Vs[row * 72 + seg] = *(const uint4*)&vbase[(size_t)row * NPAD + key0 + seg];
        }
        __syncthreads();

        for (int ci = 0; ci < 4; ci++) {
            bf16x8 kf0 = *(const bf16x8*)&Ks[(ci * 16 + l15) * 72 + quad * 8];
            bf16x8 kf1 = *(const bf16x8*)&Ks[(ci * 16 + l15) * 72 + 32 + quad * 8];
            int col = key0 + ci * 16 + l15;
            float pc = pol[col];         // 0 for pad cols -> e = 0
            for (int mi = 0; mi < 2; mi++) {
                f32x4 a = {};
                a = mfma16(qf[mi][0], kf0, a);
                a = mfma16(qf[mi][1], kf1, a);
                for (int r = 0; r < 4; r++) {
                    float ap = (col == rowtok0[mi] + r) ? 1.f : pc;
                    float e = __expf(a[r] * SCALE) * ap;
                    Ps[wave][(mi * 16 + quad * 4 + r) * 72 + ci * 16 + l15] = f2bf_trunc(e);
                }
            }
        }
        __asm__ volatile("s_waitcnt lgkmcnt(0)" ::: "memory");  // own-wave Ps visibility
        bf16x8 pf[2][2];
        for (int mi = 0; mi < 2; mi++) {
            pf[mi][0] = *(const bf16x8*)&Ps[wave][(mi * 16 + l15) * 72 + quad * 8];
            pf[mi][1] = *(const bf16x8*)&Ps[wave][(mi * 16 + l15) * 72 + 32 + quad * 8];
            ls[mi] = mfma16(pf[mi][0], onesf, ls[mi]);
            ls[mi] = mfma16(pf[mi][1], onesf, ls[mi]);
        }
        for (int di = 0; di < 4; di++) {
            bf16x8 vf0 = *(const bf16x8*)&Vs[(di * 16 + l15) * 72 + quad * 8];
            bf16x8 vf1 = *(const bf16x8*)&Vs[(di * 16 + l15) * 72 + 32 + quad * 8];
            for (int mi = 0; mi < 2; mi++) {
                o[mi][di] = mfma16(pf[mi][0], vf0, o[mi][di]);
                o[mi][di] = mfma16(pf[mi][1], vf1, o[mi][di]);
            }
        }
        __syncthreads();
    }

    for (int mi = 0; mi < 2; mi++) {
        for (int r = 0; r < 4; r++) {
            int tok = rowtok0[mi] + r;
            if (tok < NTOK) {
                float inv = __builtin_amdgcn_rcpf(ls[mi][r] + EPSV);
                for (int di = 0; di < 4; di++) {
                    float val = o[mi][di][r] * inv;
                    ao[((size_t)(b * NTOK + tok)) * 768 + h * 64 + di * 16 + l15] = f2bf(val);
                }
            }
        }
    }
}

// ------------------------------------------------------------------ launch
extern "C" void kernel_launch(void* const* d_in, const int* in_sizes, int n_in,
                              void* d_out, int out_size, void* d_ws, size_t ws_size,
                              hipStream_t stream) {
    const float* x      = (const float*)d_in[0];
    const float* policy = (const float*)d_in[1];
    const float* Wqkv   = (const float*)d_in[2];
    const float* bqkv   = (const float*)d_in[3];
    const float* Wproj  = (const float*)d_in[4];
    const float* bproj  = (const float*)d_in[5];
    float* out = (float*)d_out;

    // workspace carve. xb/ao alias (xb dead before ao written). GEMM A-tiles
    // over-read <=172KB past xb/ao (absorbed by wqkvt); attention over-reads
    // <=300KB past qkvb (absorbed by vt).
    unsigned short* p = (unsigned short*)d_ws;
    unsigned short* xb     = p;
    unsigned short* ao     = p; p += (size_t)NROWS * 768;
    unsigned short* wqkvt  = p; p += (size_t)QKVC * 768;
    unsigned short* wprojt = p; p += (size_t)768 * 768;
    unsigned short* qkvb   = p; p += (size_t)NROWS * QKVC;
    unsigned short* vt     = p; p += (size_t)NBATCH * NHEAD * 64 * NPAD;

    k_convert_x<<<(NROWS * 768 / 4) / 256, 256, 0, stream>>>(x, xb);
    k_transpose_w<<<dim3(QKVC / 64, 768 / 64), 256, 0, stream>>>(Wqkv, wqkvt, 768, QKVC);
    k_transpose_w<<<dim3(768 / 64, 768 / 64), 256, 0, stream>>>(Wproj, wprojt, 768, 768);
    k_gemm<false><<<dim3((NROWS + 127) / 128, QKVC / 128), 256, 0, stream>>>(
        xb, wqkvt, bqkv, (void*)qkvb, QKVC);
    k_vtrans<<<dim3(NPAD / 64, NHEAD, NBATCH), 256, 0, stream>>>(qkvb, vt);
    k_attn<<<dim3(NPAD / 128, NHEAD, NBATCH), 256, 0, stream>>>(qkvb, vt, policy, ao);
    k_gemm<true><<<dim3((NROWS + 127) / 128, 768 / 128), 256, 0, stream>>>(
        ao, wprojt, bproj, (void*)out, 768);
}

// Round 5
// 246.790 us; speedup vs baseline: 1.3866x; 1.3866x over previous
//
#include <hip/hip_runtime.h>
#include <hip/hip_bf16.h>

#define QKVC   2304
#define NHEAD  12
#define NTOK   577
#define NBATCH 16
#define NROWS  (NBATCH * NTOK)   // 9232
#define NPAD   640
#define SCALE  0.125f
#define EPSV   1e-6f

typedef __bf16  bf16x8 __attribute__((ext_vector_type(8)));
typedef float   f32x4  __attribute__((ext_vector_type(4)));

__device__ __forceinline__ unsigned short f2bf(float f) {
    union { float f; unsigned u; } v; v.f = f;
    unsigned r = v.u + 0x7FFFu + ((v.u >> 16) & 1u);   // RNE
    return (unsigned short)(r >> 16);
}
__device__ __forceinline__ unsigned short f2bf_trunc(float f) {
    return (unsigned short)(__float_as_uint(f) >> 16);  // e>=0 only
}
__device__ __forceinline__ f32x4 mfma16(bf16x8 a, bf16x8 b, f32x4 c) {
    return __builtin_amdgcn_mfma_f32_16x16x32_bf16(a, b, c, 0, 0, 0);
}

// async global->LDS, 16B/lane; LDS dest = wave-uniform base + lane*16
#define GLDS16(g, l) __builtin_amdgcn_global_load_lds( \
    (const __attribute__((address_space(1))) unsigned int*)(g), \
    (__attribute__((address_space(3))) unsigned int*)(l), 16, 0, 0)

// ---------------------------------------------------------------- x -> bf16
__global__ void k_convert_x(const float* __restrict__ x, unsigned short* __restrict__ xb) {
    int idx = blockIdx.x * 256 + threadIdx.x;
    float4 v = ((const float4*)x)[idx];
    ushort4 o;
    o.x = f2bf(v.x); o.y = f2bf(v.y); o.z = f2bf(v.z); o.w = f2bf(v.w);
    ((ushort4*)xb)[idx] = o;
}

// ------------------------------------------- W[K][N] fp32 -> Wt[N][K] bf16
__global__ void k_transpose_w(const float* __restrict__ src, unsigned short* __restrict__ dst,
                              int K, int N) {
    __shared__ unsigned short lt[64 * 72];
    int t  = threadIdx.x;
    int n0 = blockIdx.x * 64, k0 = blockIdx.y * 64;
    int kk = t >> 4, nn = (t & 15) * 4;
    for (int i = 0; i < 4; i++) {
        int kr = kk + i * 16;
        float4 v = *(const float4*)&src[(size_t)(k0 + kr) * N + n0 + nn];
        lt[(nn + 0) * 72 + kr] = f2bf(v.x);
        lt[(nn + 1) * 72 + kr] = f2bf(v.y);
        lt[(nn + 2) * 72 + kr] = f2bf(v.z);
        lt[(nn + 3) * 72 + kr] = f2bf(v.w);
    }
    __syncthreads();
    int n = t >> 2, seg = (t & 3) * 16;
    uint4 a = *(uint4*)&lt[n * 72 + seg];
    uint4 b = *(uint4*)&lt[n * 72 + seg + 8];
    *(uint4*)&dst[(size_t)(n0 + n) * K + k0 + seg]     = a;
    *(uint4*)&dst[(size_t)(n0 + n) * K + k0 + seg + 8] = b;
}

// -------------------------------------------------- 128x128 GEMM, K=768
// Triple-buffered LDS fed by global_load_lds; AITER-style pipeline:
// raw s_barrier + s_waitcnt vmcnt(4) keeps the NEXT iter's 4 loads in flight
// across the barrier (never drains to 0 until the last iter). Loads for kt+2
// are issued AFTER barrier kt, when all waves are done reading buf[(kt-1)%3]
// (== the write target (kt+2)%3).
template <bool F32OUT>
__global__ __launch_bounds__(256, 3)
void k_gemm(const unsigned short* __restrict__ A, const unsigned short* __restrict__ B,
            const float* __restrict__ bias, void* __restrict__ outp, int Ncols) {
    __shared__ unsigned short As[3][128 * 32];   // 3 x 8KB, 64B rows (glds layout)
    __shared__ unsigned short Bs[3][128 * 32];   // total 48KB -> 3 blocks/CU
    int t = threadIdx.x;
    int lane = t & 63, wave = t >> 6, quad = lane >> 4, l15 = lane & 15;
    int wm = wave >> 1, wn = wave & 1;
    int m0 = blockIdx.x * 128, n0 = blockIdx.y * 128;

    // per-lane global src (row = chunkbase + lane>>2, seg = (lane&3)*8 u16)
    const unsigned short* ga0 = A + (size_t)(m0 + wave * 32 + (lane >> 2)) * 768 + (lane & 3) * 8;
    const unsigned short* ga1 = ga0 + (size_t)16 * 768;
    const unsigned short* gb0 = B + (size_t)(n0 + wave * 32 + (lane >> 2)) * 768 + (lane & 3) * 8;
    const unsigned short* gb1 = gb0 + (size_t)16 * 768;
    unsigned lo = wave * 1024;   // u16 offset of this wave's 32-row chunk

    f32x4 acc[4][4] = {};

    // prologue: buffers for kt=0,1 (8 glds/wave outstanding)
    GLDS16(ga0,      &As[0][lo]); GLDS16(ga1,      &As[0][lo + 512]);
    GLDS16(gb0,      &Bs[0][lo]); GLDS16(gb1,      &Bs[0][lo + 512]);
    GLDS16(ga0 + 32, &As[1][lo]); GLDS16(ga1 + 32, &As[1][lo + 512]);
    GLDS16(gb0 + 32, &Bs[1][lo]); GLDS16(gb1 + 32, &Bs[1][lo + 512]);

    #pragma unroll 3
    for (int kt = 0; kt < 24; kt++) {
        int buf = kt % 3;
        if (kt == 23) { asm volatile("s_waitcnt vmcnt(0)" ::: "memory"); }
        else          { asm volatile("s_waitcnt vmcnt(4)" ::: "memory"); }
        asm volatile("s_barrier" ::: "memory");
        if (kt < 22) {
            int nb = buf + 2; if (nb >= 3) nb -= 3;
            int ko = (kt + 2) * 32;
            GLDS16(ga0 + ko, &As[nb][lo]); GLDS16(ga1 + ko, &As[nb][lo + 512]);
            GLDS16(gb0 + ko, &Bs[nb][lo]); GLDS16(gb1 + ko, &Bs[nb][lo + 512]);
        }
        bf16x8 af[4], bfr[4];
        for (int i = 0; i < 4; i++) {
            af[i]  = *(const bf16x8*)&As[buf][(wm * 64 + i * 16 + l15) * 32 + quad * 8];
            bfr[i] = *(const bf16x8*)&Bs[buf][(wn * 64 + i * 16 + l15) * 32 + quad * 8];
        }
        for (int mi = 0; mi < 4; mi++)
            for (int ni = 0; ni < 4; ni++)
                acc[mi][ni] = mfma16(af[mi], bfr[ni], acc[mi][ni]);
    }
    asm volatile("" ::: "memory");   // keep epilogue loads out of the loop's vmcnt count

    for (int ni = 0; ni < 4; ni++) {
        int col = n0 + wn * 64 + ni * 16 + l15;
        float bv = bias[col];
        for (int mi = 0; mi < 4; mi++) {
            int rowm = m0 + wm * 64 + mi * 16 + quad * 4;
            for (int r = 0; r < 4; r++) {
                int m = rowm + r;
                if (m < NROWS) {
                    if constexpr (F32OUT)
                        ((float*)outp)[(size_t)m * Ncols + col] = acc[mi][ni][r] + bv;
                    else
                        ((unsigned short*)outp)[(size_t)m * Ncols + col] = f2bf(acc[mi][ni][r] + bv);
                }
            }
        }
    }
}

// -------------------------------------------- V slice of qkv -> V^T [d][tok]
__global__ void k_vtrans(const unsigned short* __restrict__ qkv, unsigned short* __restrict__ vt) {
    __shared__ unsigned short lt[64 * 72];
    int t = threadIdx.x;
    int b = blockIdx.z, h = blockIdx.y, tt = blockIdx.x;
    for (int i = t; i < 512; i += 256) {
        int row = i >> 3, seg = (i & 7) * 8;
        int tok = tt * 64 + row;
        uint4 v = {0, 0, 0, 0};
        if (tok < NTOK)
            v = *(const uint4*)&qkv[(size_t)(b * NTOK + tok) * QKVC + 1536 + h * 64 + seg];
        *(uint4*)&lt[row * 72 + seg] = v;
    }
    __syncthreads();
    for (int i = t; i < 512; i += 256) {
        int d = i >> 3, ts = i & 7;
        unsigned short tmp[8];
        for (int j = 0; j < 8; j++) tmp[j] = lt[(ts * 8 + j) * 72 + d];
        *(uint4*)&vt[((size_t)((b * NHEAD + h) * 64) + d) * NPAD + tt * 64 + ts * 8] =
            *(uint4*)tmp;
    }
}

// --------------------------------------------------------- flash attention
// 128 q-rows per block; Q-frags direct global->VGPR; no max-subtraction
// (scores bounded); row-sum via ones-MFMA. ~10us total, keep as-is.
__global__ __launch_bounds__(256, 4)
void k_attn(const unsigned short* __restrict__ qkv, const unsigned short* __restrict__ vt,
            const float* __restrict__ policy, unsigned short* __restrict__ ao) {
    __shared__ unsigned short Ks[64 * 72];
    __shared__ unsigned short Vs[64 * 72];     // V^T tile [d][key]
    __shared__ unsigned short Ps[4][32 * 72];  // per-wave P tile [row][key]
    __shared__ float pol[NPAD];
    int t = threadIdx.x;
    int lane = t & 63, wave = t >> 6, quad = lane >> 4, l15 = lane & 15;
    int b = blockIdx.z, h = blockIdx.y, qt = blockIdx.x;
    const unsigned short* qbase = qkv + (size_t)(b * NTOK) * QKVC + h * 64;
    const unsigned short* kbase = qkv + (size_t)(b * NTOK) * QKVC + 768 + h * 64;
    const unsigned short* vbase = vt + (size_t)(b * NHEAD + h) * 64 * NPAD;

    for (int i = t; i < NPAD; i += 256)
        pol[i] = (i < NTOK) ? policy[b * NTOK + i] : 0.f;

    bf16x8 qf[2][2];
    for (int mi = 0; mi < 2; mi++) {
        const unsigned short* qp =
            qbase + (size_t)(qt * 128 + mi * 64 + wave * 16 + l15) * QKVC + quad * 8;
        qf[mi][0] = *(const bf16x8*)qp;
        qf[mi][1] = *(const bf16x8*)(qp + 32);
    }
    bf16x8 onesf;
    for (int j = 0; j < 8; j++) onesf[j] = (__bf16)1.0f;
    f32x4 o[2][4] = {};
    f32x4 ls[2] = {};
    int rowtok0[2];
    for (int mi = 0; mi < 2; mi++)
        rowtok0[mi] = qt * 128 + mi * 64 + wave * 16 + quad * 4;
    __syncthreads();   // pol visible

    for (int kt = 0; kt < 10; kt++) {
        int key0 = kt * 64;
        for (int i = t; i < 512; i += 256) {
            int row = i >> 3, seg = (i & 7) * 8;
            *(uint4*)&Ks[row * 72 + seg] = *(const uint4*)&kbase[(size_t)(key0 + row) * QKVC + seg];
            *(uint4*)&Vs[row * 72 + seg] = *(const uint4*)&vbase[(size_t)row * NPAD + key0 + seg];
        }
        __syncthreads();

        for (int ci = 0; ci < 4; ci++) {
            bf16x8 kf0 = *(const bf16x8*)&Ks[(ci * 16 + l15) * 72 + quad * 8];
            bf16x8 kf1 = *(const bf16x8*)&Ks[(ci * 16 + l15) * 72 + 32 + quad * 8];
            int col = key0 + ci * 16 + l15;
            float pc = pol[col];         // 0 for pad cols -> e = 0
            for (int mi = 0; mi < 2; mi++) {
                f32x4 a = {};
                a = mfma16(qf[mi][0], kf0, a);
                a = mfma16(qf[mi][1], kf1, a);
                for (int r = 0; r < 4; r++) {
                    float ap = (col == rowtok0[mi] + r) ? 1.f : pc;
                    float e = __expf(a[r] * SCALE) * ap;
                    Ps[wave][(mi * 16 + quad * 4 + r) * 72 + ci * 16 + l15] = f2bf_trunc(e);
                }
            }
        }
        __asm__ volatile("s_waitcnt lgkmcnt(0)" ::: "memory");  // own-wave Ps visibility
        bf16x8 pf[2][2];
        for (int mi = 0; mi < 2; mi++) {
            pf[mi][0] = *(const bf16x8*)&Ps[wave][(mi * 16 + l15) * 72 + quad * 8];
            pf[mi][1] = *(const bf16x8*)&Ps[wave][(mi * 16 + l15) * 72 + 32 + quad * 8];
            ls[mi] = mfma16(pf[mi][0], onesf, ls[mi]);
            ls[mi] = mfma16(pf[mi][1], onesf, ls[mi]);
        }
        for (int di = 0; di < 4; di++) {
            bf16x8 vf0 = *(const bf16x8*)&Vs[(di * 16 + l15) * 72 + quad * 8];
            bf16x8 vf1 = *(const bf16x8*)&Vs[(di * 16 + l15) * 72 + 32 + quad * 8];
            for (int mi = 0; mi < 2; mi++) {
                o[mi][di] = mfma16(pf[mi][0], vf0, o[mi][di]);
                o[mi][di] = mfma16(pf[mi][1], vf1, o[mi][di]);
            }
        }
        __syncthreads();
    }

    for (int mi = 0; mi < 2; mi++) {
        for (int r = 0; r < 4; r++) {
            int tok = rowtok0[mi] + r;
            if (tok < NTOK) {
                float inv = __builtin_amdgcn_rcpf(ls[mi][r] + EPSV);
                for (int di = 0; di < 4; di++) {
                    float val = o[mi][di][r] * inv;
                    ao[((size_t)(b * NTOK + tok)) * 768 + h * 64 + di * 16 + l15] = f2bf(val);
                }
            }
        }
    }
}

// ------------------------------------------------------------------ launch
extern "C" void kernel_launch(void* const* d_in, const int* in_sizes, int n_in,
                              void* d_out, int out_size, void* d_ws, size_t ws_size,
                              hipStream_t stream) {
    const float* x      = (const float*)d_in[0];
    const float* policy = (const float*)d_in[1];
    const float* Wqkv   = (const float*)d_in[2];
    const float* bqkv   = (const float*)d_in[3];
    const float* Wproj  = (const float*)d_in[4];
    const float* bproj  = (const float*)d_in[5];
    float* out = (float*)d_out;

    // workspace carve. xb/ao alias (xb dead before ao written). GEMM A-tiles
    // over-read <=172KB past xb/ao (absorbed by wqkvt); attention over-reads
    // <=300KB past qkvb (absorbed by vt).
    unsigned short* p = (unsigned short*)d_ws;
    unsigned short* xb     = p;
    unsigned short* ao     = p; p += (size_t)NROWS * 768;
    unsigned short* wqkvt  = p; p += (size_t)QKVC * 768;
    unsigned short* wprojt = p; p += (size_t)768 * 768;
    unsigned short* qkvb   = p; p += (size_t)NROWS * QKVC;
    unsigned short* vt     = p; p += (size_t)NBATCH * NHEAD * 64 * NPAD;

    k_convert_x<<<(NROWS * 768 / 4) / 256, 256, 0, stream>>>(x, xb);
    k_transpose_w<<<dim3(QKVC / 64, 768 / 64), 256, 0, stream>>>(Wqkv, wqkvt, 768, QKVC);
    k_transpose_w<<<dim3(768 / 64, 768 / 64), 256, 0, stream>>>(Wproj, wprojt, 768, 768);
    k_gemm<false><<<dim3((NROWS + 127) / 128, QKVC / 128), 256, 0, stream>>>(
        xb, wqkvt, bqkv, (void*)qkvb, QKVC);
    k_vtrans<<<dim3(NPAD / 64, NHEAD, NBATCH), 256, 0, stream>>>(qkvb, vt);
    k_attn<<<dim3(NPAD / 128, NHEAD, NBATCH), 256, 0, stream>>>(qkvb, vt, policy, ao);
    k_gemm<true><<<dim3((NROWS + 127) / 128, 768 / 128), 256, 0, stream>>>(
        ao, wprojt, bproj, (void*)out, 768);
}

// Round 6
// 216.110 us; speedup vs baseline: 1.5834x; 1.1420x over previous
//
#include <hip/hip_runtime.h>
#include <hip/hip_bf16.h>

#define QKVC   2304
#define NHEAD  12
#define NTOK   577
#define NBATCH 16
#define NROWS  (NBATCH * NTOK)   // 9232
#define NPAD   640
#define SCALE  0.125f
#define EPSV   1e-6f

typedef __bf16  bf16x8 __attribute__((ext_vector_type(8)));
typedef float   f32x4  __attribute__((ext_vector_type(4)));

__device__ __forceinline__ unsigned short f2bf(float f) {
    union { float f; unsigned u; } v; v.f = f;
    unsigned r = v.u + 0x7FFFu + ((v.u >> 16) & 1u);   // RNE
    return (unsigned short)(r >> 16);
}
__device__ __forceinline__ unsigned short f2bf_trunc(float f) {
    return (unsigned short)(__float_as_uint(f) >> 16);  // e>=0 only
}
__device__ __forceinline__ f32x4 mfma16(bf16x8 a, bf16x8 b, f32x4 c) {
    return __builtin_amdgcn_mfma_f32_16x16x32_bf16(a, b, c, 0, 0, 0);
}

// async global->LDS, 16B/lane; LDS dest = wave-uniform base + lane*16
#define GLDS16(g, l) __builtin_amdgcn_global_load_lds( \
    (const __attribute__((address_space(1))) unsigned int*)(g), \
    (__attribute__((address_space(3))) unsigned int*)(l), 16, 0, 0)

// ---------------------------------------------------------------- x -> bf16
__global__ void k_convert_x(const float* __restrict__ x, unsigned short* __restrict__ xb) {
    int idx = blockIdx.x * 256 + threadIdx.x;
    float4 v = ((const float4*)x)[idx];
    ushort4 o;
    o.x = f2bf(v.x); o.y = f2bf(v.y); o.z = f2bf(v.z); o.w = f2bf(v.w);
    ((ushort4*)xb)[idx] = o;
}

// ------------------------------------------- W[K][N] fp32 -> Wt[N][K] bf16
__global__ void k_transpose_w(const float* __restrict__ src, unsigned short* __restrict__ dst,
                              int K, int N) {
    __shared__ unsigned short lt[64 * 72];
    int t  = threadIdx.x;
    int n0 = blockIdx.x * 64, k0 = blockIdx.y * 64;
    int kk = t >> 4, nn = (t & 15) * 4;
    for (int i = 0; i < 4; i++) {
        int kr = kk + i * 16;
        float4 v = *(const float4*)&src[(size_t)(k0 + kr) * N + n0 + nn];
        lt[(nn + 0) * 72 + kr] = f2bf(v.x);
        lt[(nn + 1) * 72 + kr] = f2bf(v.y);
        lt[(nn + 2) * 72 + kr] = f2bf(v.z);
        lt[(nn + 3) * 72 + kr] = f2bf(v.w);
    }
    __syncthreads();
    int n = t >> 2, seg = (t & 3) * 16;
    uint4 a = *(uint4*)&lt[n * 72 + seg];
    uint4 b = *(uint4*)&lt[n * 72 + seg + 8];
    *(uint4*)&dst[(size_t)(n0 + n) * K + k0 + seg]     = a;
    *(uint4*)&dst[(size_t)(n0 + n) * K + k0 + seg + 8] = b;
}

// -------------------------------------------------- 128x128 GEMM, K=768
// Grid is 1D with XCD-stripe mapping: id&7 selects the m-tile within a group
// of 8; with round-robin block->XCD dispatch each XCD sees a FIXED m-stripe
// and walks all n => per-XCD L2 working set = 1 A-tile + whole B panel < 4MB.
// Triple-buffered LDS + glds width16; s_waitcnt vmcnt(4) keeps next iter's
// loads in flight across the raw s_barrier (2-iter prefetch distance).
// bf16 output goes through an LDS repack so stores are full-line dwordx4.
template <bool F32OUT>
__global__ __launch_bounds__(256, 3)
void k_gemm(const unsigned short* __restrict__ A, const unsigned short* __restrict__ B,
            const float* __restrict__ bias, void* __restrict__ outp, int Ncols) {
    __shared__ unsigned short SL[24576];   // 48KB: 3x(As+Bs) bufs; epilogue repack tile
    unsigned short (*As)[4096] = (unsigned short (*)[4096])SL;
    unsigned short (*Bs)[4096] = (unsigned short (*)[4096])&SL[12288];
    int t = threadIdx.x;
    int lane = t & 63, wave = t >> 6, quad = lane >> 4, l15 = lane & 15;
    int wm = wave >> 1, wn = wave & 1;
    int nT = Ncols >> 7;
    int mLocal = blockIdx.x & 7;
    int rest = blockIdx.x >> 3;
    int n0 = (rest % nT) * 128;
    int m0 = ((rest / nT) * 8 + mLocal) * 128;

    // per-lane global src (row = chunkbase + lane>>2, seg = (lane&3)*8 u16)
    const unsigned short* ga0 = A + (size_t)(m0 + wave * 32 + (lane >> 2)) * 768 + (lane & 3) * 8;
    const unsigned short* ga1 = ga0 + (size_t)16 * 768;
    const unsigned short* gb0 = B + (size_t)(n0 + wave * 32 + (lane >> 2)) * 768 + (lane & 3) * 8;
    const unsigned short* gb1 = gb0 + (size_t)16 * 768;
    unsigned lo = wave * 1024;   // u16 offset of this wave's 32-row chunk

    f32x4 acc[4][4] = {};

    // prologue: buffers for kt=0,1 (8 glds/wave outstanding)
    GLDS16(ga0,      &As[0][lo]); GLDS16(ga1,      &As[0][lo + 512]);
    GLDS16(gb0,      &Bs[0][lo]); GLDS16(gb1,      &Bs[0][lo + 512]);
    GLDS16(ga0 + 32, &As[1][lo]); GLDS16(ga1 + 32, &As[1][lo + 512]);
    GLDS16(gb0 + 32, &Bs[1][lo]); GLDS16(gb1 + 32, &Bs[1][lo + 512]);

    #pragma unroll 3
    for (int kt = 0; kt < 24; kt++) {
        int buf = kt % 3;
        if (kt == 23) { asm volatile("s_waitcnt vmcnt(0)" ::: "memory"); }
        else          { asm volatile("s_waitcnt vmcnt(4)" ::: "memory"); }
        asm volatile("s_barrier" ::: "memory");
        if (kt < 22) {
            int nb = buf + 2; if (nb >= 3) nb -= 3;
            int ko = (kt + 2) * 32;
            GLDS16(ga0 + ko, &As[nb][lo]); GLDS16(ga1 + ko, &As[nb][lo + 512]);
            GLDS16(gb0 + ko, &Bs[nb][lo]); GLDS16(gb1 + ko, &Bs[nb][lo + 512]);
        }
        bf16x8 af[4], bfr[4];
        for (int i = 0; i < 4; i++) {
            af[i]  = *(const bf16x8*)&As[buf][(wm * 64 + i * 16 + l15) * 32 + quad * 8];
            bfr[i] = *(const bf16x8*)&Bs[buf][(wn * 64 + i * 16 + l15) * 32 + quad * 8];
        }
        for (int mi = 0; mi < 4; mi++)
            for (int ni = 0; ni < 4; ni++)
                acc[mi][ni] = mfma16(af[mi], bfr[ni], acc[mi][ni]);
    }
    asm volatile("" ::: "memory");   // keep epilogue loads out of the loop's vmcnt count

    if constexpr (F32OUT) {
        for (int ni = 0; ni < 4; ni++) {
            int col = n0 + wn * 64 + ni * 16 + l15;
            float bv = bias[col];
            for (int mi = 0; mi < 4; mi++) {
                int rowm = m0 + wm * 64 + mi * 16 + quad * 4;
                for (int r = 0; r < 4; r++) {
                    int m = rowm + r;
                    if (m < NROWS)
                        ((float*)outp)[(size_t)m * Ncols + col] = acc[mi][ni][r] + bv;
                }
            }
        }
    } else {
        // repack 128x128 bf16 tile through LDS (stride 132 u16 = 264B:
        // quad rows step banks by 8 -> 2-way on write), then dwordx4 stores
        // covering full 256B rows.
        __syncthreads();   // all waves past their LDS fragment reads
        for (int ni = 0; ni < 4; ni++) {
            int colL = wn * 64 + ni * 16 + l15;
            float bv = bias[n0 + colL];
            for (int mi = 0; mi < 4; mi++) {
                int rowL = wm * 64 + mi * 16 + quad * 4;
                for (int r = 0; r < 4; r++)
                    SL[(rowL + r) * 132 + colL] = f2bf(acc[mi][ni][r] + bv);
            }
        }
        __syncthreads();
        for (int rr = 0; rr < 8; rr++) {
            int row = rr * 16 + (t >> 4);
            int m = m0 + row;
            if (m < NROWS) {
                uint4 v = *(uint4*)&SL[row * 132 + (t & 15) * 8];
                *(uint4*)&((unsigned short*)outp)[(size_t)m * Ncols + n0 + (t & 15) * 8] = v;
            }
        }
    }
}

// -------------------------------------------- V slice of qkv -> V^T [d][tok]
__global__ void k_vtrans(const unsigned short* __restrict__ qkv, unsigned short* __restrict__ vt) {
    __shared__ unsigned short lt[64 * 72];
    int t = threadIdx.x;
    int b = blockIdx.z, h = blockIdx.y, tt = blockIdx.x;
    for (int i = t; i < 512; i += 256) {
        int row = i >> 3, seg = (i & 7) * 8;
        int tok = tt * 64 + row;
        uint4 v = {0, 0, 0, 0};
        if (tok < NTOK)
            v = *(const uint4*)&qkv[(size_t)(b * NTOK + tok) * QKVC + 1536 + h * 64 + seg];
        *(uint4*)&lt[row * 72 + seg] = v;
    }
    __syncthreads();
    for (int i = t; i < 512; i += 256) {
        int d = i >> 3, ts = i & 7;
        unsigned short tmp[8];
        for (int j = 0; j < 8; j++) tmp[j] = lt[(ts * 8 + j) * 72 + d];
        *(uint4*)&vt[((size_t)((b * NHEAD + h) * 64) + d) * NPAD + tt * 64 + ts * 8] =
            *(uint4*)tmp;
    }
}

// --------------------------------------------------------- flash attention
// 128 q-rows per block; Q-frags direct global->VGPR; no max-subtraction
// (scores bounded); row-sum via ones-MFMA. ~10us, keep as-is.
__global__ __launch_bounds__(256, 4)
void k_attn(const unsigned short* __restrict__ qkv, const unsigned short* __restrict__ vt,
            const float* __restrict__ policy, unsigned short* __restrict__ ao) {
    __shared__ unsigned short Ks[64 * 72];
    __shared__ unsigned short Vs[64 * 72];     // V^T tile [d][key]
    __shared__ unsigned short Ps[4][32 * 72];  // per-wave P tile [row][key]
    __shared__ float pol[NPAD];
    int t = threadIdx.x;
    int lane = t & 63, wave = t >> 6, quad = lane >> 4, l15 = lane & 15;
    int b = blockIdx.z, h = blockIdx.y, qt = blockIdx.x;
    const unsigned short* qbase = qkv + (size_t)(b * NTOK) * QKVC + h * 64;
    const unsigned short* kbase = qkv + (size_t)(b * NTOK) * QKVC + 768 + h * 64;
    const unsigned short* vbase = vt + (size_t)(b * NHEAD + h) * 64 * NPAD;

    for (int i = t; i < NPAD; i += 256)
        pol[i] = (i < NTOK) ? policy[b * NTOK + i] : 0.f;

    bf16x8 qf[2][2];
    for (int mi = 0; mi < 2; mi++) {
        const unsigned short* qp =
            qbase + (size_t)(qt * 128 + mi * 64 + wave * 16 + l15) * QKVC + quad * 8;
        qf[mi][0] = *(const bf16x8*)qp;
        qf[mi][1] = *(const bf16x8*)(qp + 32);
    }
    bf16x8 onesf;
    for (int j = 0; j < 8; j++) onesf[j] = (__bf16)1.0f;
    f32x4 o[2][4] = {};
    f32x4 ls[2] = {};
    int rowtok0[2];
    for (int mi = 0; mi < 2; mi++)
        rowtok0[mi] = qt * 128 + mi * 64 + wave * 16 + quad * 4;
    __syncthreads();   // pol visible

    for (int kt = 0; kt < 10; kt++) {
        int key0 = kt * 64;
        for (int i = t; i < 512; i += 256) {
            int row = i >> 3, seg = (i & 7) * 8;
            *(uint4*)&Ks[row * 72 + seg] = *(const uint4*)&kbase[(size_t)(key0 + row) * QKVC + seg];
            *(uint4*)&Vs[row * 72 + seg] = *(const uint4*)&vbase[(size_t)row * NPAD + key0 + seg];
        }
        __syncthreads();

        for (int ci = 0; ci < 4; ci++) {
            bf16x8 kf0 = *(const bf16x8*)&Ks[(ci * 16 + l15) * 72 + quad * 8];
            bf16x8 kf1 = *(const bf16x8*)&Ks[(ci * 16 + l15) * 72 + 32 + quad * 8];
            int col = key0 + ci * 16 + l15;
            float pc = pol[col];         // 0 for pad cols -> e = 0
            for (int mi = 0; mi < 2; mi++) {
                f32x4 a = {};
                a = mfma16(qf[mi][0], kf0, a);
                a = mfma16(qf[mi][1], kf1, a);
                for (int r = 0; r < 4; r++) {
                    float ap = (col == rowtok0[mi] + r) ? 1.f : pc;
                    float e = __expf(a[r] * SCALE) * ap;
                    Ps[wave][(mi * 16 + quad * 4 + r) * 72 + ci * 16 + l15] = f2bf_trunc(e);
                }
            }
        }
        __asm__ volatile("s_waitcnt lgkmcnt(0)" ::: "memory");  // own-wave Ps visibility
        bf16x8 pf[2][2];
        for (int mi = 0; mi < 2; mi++) {
            pf[mi][0] = *(const bf16x8*)&Ps[wave][(mi * 16 + l15) * 72 + quad * 8];
            pf[mi][1] = *(const bf16x8*)&Ps[wave][(mi * 16 + l15) * 72 + 32 + quad * 8];
            ls[mi] = mfma16(pf[mi][0], onesf, ls[mi]);
            ls[mi] = mfma16(pf[mi][1], onesf, ls[mi]);
        }
        for (int di = 0; di < 4; di++) {
            bf16x8 vf0 = *(const bf16x8*)&Vs[(di * 16 + l15) * 72 + quad * 8];
            bf16x8 vf1 = *(const bf16x8*)&Vs[(di * 16 + l15) * 72 + 32 + quad * 8];
            for (int mi = 0; mi < 2; mi++) {
                o[mi][di] = mfma16(pf[mi][0], vf0, o[mi][di]);
                o[mi][di] = mfma16(pf[mi][1], vf1, o[mi][di]);
            }
        }
        __syncthreads();
    }

    for (int mi = 0; mi < 2; mi++) {
        for (int r = 0; r < 4; r++) {
            int tok = rowtok0[mi] + r;
            if (tok < NTOK) {
                float inv = __builtin_amdgcn_rcpf(ls[mi][r] + EPSV);
                for (int di = 0; di < 4; di++) {
                    float val = o[mi][di][r] * inv;
                    ao[((size_t)(b * NTOK + tok)) * 768 + h * 64 + di * 16 + l15] = f2bf(val);
                }
            }
        }
    }
}

// ------------------------------------------------------------------ launch
extern "C" void kernel_launch(void* const* d_in, const int* in_sizes, int n_in,
                              void* d_out, int out_size, void* d_ws, size_t ws_size,
                              hipStream_t stream) {
    const float* x      = (const float*)d_in[0];
    const float* policy = (const float*)d_in[1];
    const float* Wqkv   = (const float*)d_in[2];
    const float* bqkv   = (const float*)d_in[3];
    const float* Wproj  = (const float*)d_in[4];
    const float* bproj  = (const float*)d_in[5];
    float* out = (float*)d_out;

    // workspace carve. xb/ao alias (xb dead before ao written). GEMM A-staging
    // over-reads up to m-tile 79 (row 10240 = 15.7MB) past xb/ao start --
    // absorbed by wqkvt+wprojt (18.9MB cumulative). Attention over-reads
    // <=300KB past qkvb (absorbed by vt).
    unsigned short* p = (unsigned short*)d_ws;
    unsigned short* xb     = p;
    unsigned short* ao     = p; p += (size_t)NROWS * 768;
    unsigned short* wqkvt  = p; p += (size_t)QKVC * 768;
    unsigned short* wprojt = p; p += (size_t)768 * 768;
    unsigned short* qkvb   = p; p += (size_t)NROWS * QKVC;
    unsigned short* vt     = p; p += (size_t)NBATCH * NHEAD * 64 * NPAD;

    int mT = (NROWS + 127) / 128;   // 73
    int mG = (mT + 7) / 8;          // 10 groups of 8 m-tiles (XCD stripes)

    k_convert_x<<<(NROWS * 768 / 4) / 256, 256, 0, stream>>>(x, xb);
    k_transpose_w<<<dim3(QKVC / 64, 768 / 64), 256, 0, stream>>>(Wqkv, wqkvt, 768, QKVC);
    k_transpose_w<<<dim3(768 / 64, 768 / 64), 256, 0, stream>>>(Wproj, wprojt, 768, 768);
    k_gemm<false><<<mG * 8 * (QKVC / 128), 256, 0, stream>>>(
        xb, wqkvt, bqkv, (void*)qkvb, QKVC);
    k_vtrans<<<dim3(NPAD / 64, NHEAD, NBATCH), 256, 0, stream>>>(qkvb, vt);
    k_attn<<<dim3(NPAD / 128, NHEAD, NBATCH), 256, 0, stream>>>(qkvb, vt, policy, ao);
    k_gemm<true><<<mG * 8 * (768 / 128), 256, 0, stream>>>(
        ao, wprojt, bproj, (void*)out, 768);
}

// Round 7
// 215.272 us; speedup vs baseline: 1.5896x; 1.0039x over previous
//
#include <hip/hip_runtime.h>
#include <hip/hip_bf16.h>

#define QKVC   2304
#define NHEAD  12
#define NTOK   577
#define NBATCH 16
#define NROWS  (NBATCH * NTOK)   // 9232
#define NPAD   640
#define SCALE  0.125f
#define EPSV   1e-6f

typedef __bf16  bf16x8 __attribute__((ext_vector_type(8)));
typedef float   f32x4  __attribute__((ext_vector_type(4)));

__device__ __forceinline__ unsigned short f2bf(float f) {
    union { float f; unsigned u; } v; v.f = f;
    unsigned r = v.u + 0x7FFFu + ((v.u >> 16) & 1u);   // RNE
    return (unsigned short)(r >> 16);
}
__device__ __forceinline__ unsigned short f2bf_trunc(float f) {
    return (unsigned short)(__float_as_uint(f) >> 16);  // e>=0 only
}
__device__ __forceinline__ f32x4 mfma16(bf16x8 a, bf16x8 b, f32x4 c) {
    return __builtin_amdgcn_mfma_f32_16x16x32_bf16(a, b, c, 0, 0, 0);
}

// async global->LDS, 16B/lane; LDS dest = wave-uniform base + lane*16
#define GLDS16(g, l) __builtin_amdgcn_global_load_lds( \
    (const __attribute__((address_space(1))) unsigned int*)(g), \
    (__attribute__((address_space(3))) unsigned int*)(l), 16, 0, 0)

// ---------------------------------------------------------------- x -> bf16
__global__ void k_convert_x(const float* __restrict__ x, unsigned short* __restrict__ xb) {
    int idx = blockIdx.x * 256 + threadIdx.x;
    float4 v = ((const float4*)x)[idx];
    ushort4 o;
    o.x = f2bf(v.x); o.y = f2bf(v.y); o.z = f2bf(v.z); o.w = f2bf(v.w);
    ((ushort4*)xb)[idx] = o;
}

// ------------------------------------------- W[K][N] fp32 -> Wt[N][K] bf16
__global__ void k_transpose_w(const float* __restrict__ src, unsigned short* __restrict__ dst,
                              int K, int N) {
    __shared__ unsigned short lt[64 * 72];
    int t  = threadIdx.x;
    int n0 = blockIdx.x * 64, k0 = blockIdx.y * 64;
    int kk = t >> 4, nn = (t & 15) * 4;
    for (int i = 0; i < 4; i++) {
        int kr = kk + i * 16;
        float4 v = *(const float4*)&src[(size_t)(k0 + kr) * N + n0 + nn];
        lt[(nn + 0) * 72 + kr] = f2bf(v.x);
        lt[(nn + 1) * 72 + kr] = f2bf(v.y);
        lt[(nn + 2) * 72 + kr] = f2bf(v.z);
        lt[(nn + 3) * 72 + kr] = f2bf(v.w);
    }
    __syncthreads();
    int n = t >> 2, seg = (t & 3) * 16;
    uint4 a = *(uint4*)&lt[n * 72 + seg];
    uint4 b = *(uint4*)&lt[n * 72 + seg + 8];
    *(uint4*)&dst[(size_t)(n0 + n) * K + k0 + seg]     = a;
    *(uint4*)&dst[(size_t)(n0 + n) * K + k0 + seg + 8] = b;
}

// -------------------------------------------------- 128x128 GEMM, K=768
// XCD-stripe 1D grid (id&7 = m-tile in group => per-XCD L2 working set =
// 1 A-tile + B panel < 4MB). Triple-buffered LDS + glds width16 with
// s_waitcnt vmcnt(4) raw-barrier pipeline (2-iter prefetch distance).
// XOR-SWIZZLED LDS layout: glds's LDS dest is pinned (base+lane*16), but the
// per-lane GLOBAL source is free, so LDS chunk slot c of row r holds global
// chunk c^(r&3). Fragment read addr: chunk = quad^(l15&3) -> bank =
// (4*l15 + (quad^(l15&3)))%32 = every bank exactly 2 lanes = conflict-free
// (vs 8-way = 2.94x LDS slowdown in the natural layout).
template <bool F32OUT>
__global__ __launch_bounds__(256, 3)
void k_gemm(const unsigned short* __restrict__ A, const unsigned short* __restrict__ B,
            const float* __restrict__ bias, void* __restrict__ outp, int Ncols) {
    __shared__ unsigned short SL[24576];   // 48KB: 3x(As+Bs); epilogue repack tile
    unsigned short (*As)[4096] = (unsigned short (*)[4096])SL;
    unsigned short (*Bs)[4096] = (unsigned short (*)[4096])&SL[12288];
    int t = threadIdx.x;
    int lane = t & 63, wave = t >> 6, quad = lane >> 4, l15 = lane & 15;
    int wm = wave >> 1, wn = wave & 1;
    int nT = Ncols >> 7;
    int mLocal = blockIdx.x & 7;
    int rest = blockIdx.x >> 3;
    int n0 = (rest % nT) * 128;
    int m0 = ((rest / nT) * 8 + mLocal) * 128;

    // per-lane global src with XOR-swizzled chunk: row = lane>>2,
    // chunk_slot = lane&3 holds global chunk (lane&3)^((lane>>2)&3)
    int swz = ((lane & 3) ^ ((lane >> 2) & 3)) * 8;
    const unsigned short* ga0 = A + (size_t)(m0 + wave * 32 + (lane >> 2)) * 768 + swz;
    const unsigned short* ga1 = ga0 + (size_t)16 * 768;   // rows+16: (row&3) unchanged
    const unsigned short* gb0 = B + (size_t)(n0 + wave * 32 + (lane >> 2)) * 768 + swz;
    const unsigned short* gb1 = gb0 + (size_t)16 * 768;
    unsigned lo = wave * 1024;   // u16 offset of this wave's 32-row chunk

    f32x4 acc[4][4] = {};

    // prologue: buffers for kt=0,1 (8 glds/wave outstanding)
    GLDS16(ga0,      &As[0][lo]); GLDS16(ga1,      &As[0][lo + 512]);
    GLDS16(gb0,      &Bs[0][lo]); GLDS16(gb1,      &Bs[0][lo + 512]);
    GLDS16(ga0 + 32, &As[1][lo]); GLDS16(ga1 + 32, &As[1][lo + 512]);
    GLDS16(gb0 + 32, &Bs[1][lo]); GLDS16(gb1 + 32, &Bs[1][lo + 512]);

    int rsw = (quad * 8) ^ ((l15 & 3) * 8);   // swizzled chunk offset for reads

    #pragma unroll 3
    for (int kt = 0; kt < 24; kt++) {
        int buf = kt % 3;
        if (kt == 23) { asm volatile("s_waitcnt vmcnt(0)" ::: "memory"); }
        else          { asm volatile("s_waitcnt vmcnt(4)" ::: "memory"); }
        asm volatile("s_barrier" ::: "memory");
        if (kt < 22) {
            int nb = buf + 2; if (nb >= 3) nb -= 3;
            int ko = (kt + 2) * 32;
            GLDS16(ga0 + ko, &As[nb][lo]); GLDS16(ga1 + ko, &As[nb][lo + 512]);
            GLDS16(gb0 + ko, &Bs[nb][lo]); GLDS16(gb1 + ko, &Bs[nb][lo + 512]);
        }
        bf16x8 af[4], bfr[4];
        for (int i = 0; i < 4; i++) {
            af[i]  = *(const bf16x8*)&As[buf][(wm * 64 + i * 16 + l15) * 32 + rsw];
            bfr[i] = *(const bf16x8*)&Bs[buf][(wn * 64 + i * 16 + l15) * 32 + rsw];
        }
        for (int mi = 0; mi < 4; mi++)
            for (int ni = 0; ni < 4; ni++)
                acc[mi][ni] = mfma16(af[mi], bfr[ni], acc[mi][ni]);
    }
    asm volatile("" ::: "memory");   // keep epilogue loads out of the loop's vmcnt count

    if constexpr (F32OUT) {
        for (int ni = 0; ni < 4; ni++) {
            int col = n0 + wn * 64 + ni * 16 + l15;
            float bv = bias[col];
            for (int mi = 0; mi < 4; mi++) {
                int rowm = m0 + wm * 64 + mi * 16 + quad * 4;
                for (int r = 0; r < 4; r++) {
                    int m = rowm + r;
                    if (m < NROWS)
                        ((float*)outp)[(size_t)m * Ncols + col] = acc[mi][ni][r] + bv;
                }
            }
        }
    } else {
        // repack 128x128 bf16 tile through LDS then full-line dwordx4 stores
        __syncthreads();   // all waves past their LDS fragment reads
        for (int ni = 0; ni < 4; ni++) {
            int colL = wn * 64 + ni * 16 + l15;
            float bv = bias[n0 + colL];
            for (int mi = 0; mi < 4; mi++) {
                int rowL = wm * 64 + mi * 16 + quad * 4;
                for (int r = 0; r < 4; r++)
                    SL[(rowL + r) * 132 + colL] = f2bf(acc[mi][ni][r] + bv);
            }
        }
        __syncthreads();
        for (int rr = 0; rr < 8; rr++) {
            int row = rr * 16 + (t >> 4);
            int m = m0 + row;
            if (m < NROWS) {
                uint4 v = *(uint4*)&SL[row * 132 + (t & 15) * 8];
                *(uint4*)&((unsigned short*)outp)[(size_t)m * Ncols + n0 + (t & 15) * 8] = v;
            }
        }
    }
}

// -------------------------------------------- V slice of qkv -> V^T [d][tok]
__global__ void k_vtrans(const unsigned short* __restrict__ qkv, unsigned short* __restrict__ vt) {
    __shared__ unsigned short lt[64 * 72];
    int t = threadIdx.x;
    int b = blockIdx.z, h = blockIdx.y, tt = blockIdx.x;
    for (int i = t; i < 512; i += 256) {
        int row = i >> 3, seg = (i & 7) * 8;
        int tok = tt * 64 + row;
        uint4 v = {0, 0, 0, 0};
        if (tok < NTOK)
            v = *(const uint4*)&qkv[(size_t)(b * NTOK + tok) * QKVC + 1536 + h * 64 + seg];
        *(uint4*)&lt[row * 72 + seg] = v;
    }
    __syncthreads();
    for (int i = t; i < 512; i += 256) {
        int d = i >> 3, ts = i & 7;
        unsigned short tmp[8];
        for (int j = 0; j < 8; j++) tmp[j] = lt[(ts * 8 + j) * 72 + d];
        *(uint4*)&vt[((size_t)((b * NHEAD + h) * 64) + d) * NPAD + tt * 64 + ts * 8] =
            *(uint4*)tmp;
    }
}

// --------------------------------------------------------- flash attention
// 128 q-rows per block; Q-frags direct global->VGPR; no max-subtraction
// (scores bounded); row-sum via ones-MFMA. K/V tiles at stride 72 are
// already conflict-free for b128 fragment reads.
__global__ __launch_bounds__(256, 4)
void k_attn(const unsigned short* __restrict__ qkv, const unsigned short* __restrict__ vt,
            const float* __restrict__ policy, unsigned short* __restrict__ ao) {
    __shared__ unsigned short Ks[64 * 72];
    __shared__ unsigned short Vs[64 * 72];     // V^T tile [d][key]
    __shared__ unsigned short Ps[4][32 * 72];  // per-wave P tile [row][key]
    __shared__ float pol[NPAD];
    int t = threadIdx.x;
    int lane = t & 63, wave = t >> 6, quad = lane >> 4, l15 = lane & 15;
    int b = blockIdx.z, h = blockIdx.y, qt = blockIdx.x;
    const unsigned short* qbase = qkv + (size_t)(b * NTOK) * QKVC + h * 64;
    const unsigned short* kbase = qkv + (size_t)(b * NTOK) * QKVC + 768 + h * 64;
    const unsigned short* vbase = vt + (size_t)(b * NHEAD + h) * 64 * NPAD;

    for (int i = t; i < NPAD; i += 256)
        pol[i] = (i < NTOK) ? policy[b * NTOK + i] : 0.f;

    bf16x8 qf[2][2];
    for (int mi = 0; mi < 2; mi++) {
        const unsigned short* qp =
            qbase + (size_t)(qt * 128 + mi * 64 + wave * 16 + l15) * QKVC + quad * 8;
        qf[mi][0] = *(const bf16x8*)qp;
        qf[mi][1] = *(const bf16x8*)(qp + 32);
    }
    bf16x8 onesf;
    for (int j = 0; j < 8; j++) onesf[j] = (__bf16)1.0f;
    f32x4 o[2][4] = {};
    f32x4 ls[2] = {};
    int rowtok0[2];
    for (int mi = 0; mi < 2; mi++)
        rowtok0[mi] = qt * 128 + mi * 64 + wave * 16 + quad * 4;
    __syncthreads();   // pol visible

    for (int kt = 0; kt < 10; kt++) {
        int key0 = kt * 64;
        for (int i = t; i < 512; i += 256) {
            int row = i >> 3, seg = (i & 7) * 8;
            *(uint4*)&Ks[row * 72 + seg] = *(const uint4*)&kbase[(size_t)(key0 + row) * QKVC + seg];
            *(uint4*)&Vs[row * 72 + seg] = *(const uint4*)&vbase[(size_t)row * NPAD + key0 + seg];
        }
        __syncthreads();

        for (int ci = 0; ci < 4; ci++) {
            bf16x8 kf0 = *(const bf16x8*)&Ks[(ci * 16 + l15) * 72 + quad * 8];
            bf16x8 kf1 = *(const bf16x8*)&Ks[(ci * 16 + l15) * 72 + 32 + quad * 8];
            int col = key0 + ci * 16 + l15;
            float pc = pol[col];         // 0 for pad cols -> e = 0
            for (int mi = 0; mi < 2; mi++) {
                f32x4 a = {};
                a = mfma16(qf[mi][0], kf0, a);
                a = mfma16(qf[mi][1], kf1, a);
                for (int r = 0; r < 4; r++) {
                    float ap = (col == rowtok0[mi] + r) ? 1.f : pc;
                    float e = __expf(a[r] * SCALE) * ap;
                    Ps[wave][(mi * 16 + quad * 4 + r) * 72 + ci * 16 + l15] = f2bf_trunc(e);
                }
            }
        }
        __asm__ volatile("s_waitcnt lgkmcnt(0)" ::: "memory");  // own-wave Ps visibility
        bf16x8 pf[2][2];
        for (int mi = 0; mi < 2; mi++) {
            pf[mi][0] = *(const bf16x8*)&Ps[wave][(mi * 16 + l15) * 72 + quad * 8];
            pf[mi][1] = *(const bf16x8*)&Ps[wave][(mi * 16 + l15) * 72 + 32 + quad * 8];
            ls[mi] = mfma16(pf[mi][0], onesf, ls[mi]);
            ls[mi] = mfma16(pf[mi][1], onesf, ls[mi]);
        }
        for (int di = 0; di < 4; di++) {
            bf16x8 vf0 = *(const bf16x8*)&Vs[(di * 16 + l15) * 72 + quad * 8];
            bf16x8 vf1 = *(const bf16x8*)&Vs[(di * 16 + l15) * 72 + 32 + quad * 8];
            for (int mi = 0; mi < 2; mi++) {
                o[mi][di] = mfma16(pf[mi][0], vf0, o[mi][di]);
                o[mi][di] = mfma16(pf[mi][1], vf1, o[mi][di]);
            }
        }
        __syncthreads();
    }

    for (int mi = 0; mi < 2; mi++) {
        for (int r = 0; r < 4; r++) {
            int tok = rowtok0[mi] + r;
            if (tok < NTOK) {
                float inv = __builtin_amdgcn_rcpf(ls[mi][r] + EPSV);
                for (int di = 0; di < 4; di++) {
                    float val = o[mi][di][r] * inv;
                    ao[((size_t)(b * NTOK + tok)) * 768 + h * 64 + di * 16 + l15] = f2bf(val);
                }
            }
        }
    }
}

// ------------------------------------------------------------------ launch
extern "C" void kernel_launch(void* const* d_in, const int* in_sizes, int n_in,
                              void* d_out, int out_size, void* d_ws, size_t ws_size,
                              hipStream_t stream) {
    const float* x      = (const float*)d_in[0];
    const float* policy = (const float*)d_in[1];
    const float* Wqkv   = (const float*)d_in[2];
    const float* bqkv   = (const float*)d_in[3];
    const float* Wproj  = (const float*)d_in[4];
    const float* bproj  = (const float*)d_in[5];
    float* out = (float*)d_out;

    // workspace carve. xb/ao alias (xb dead before ao written). GEMM A-staging
    // over-reads up to row 10240 (15.7MB) past xb/ao start -- absorbed by
    // wqkvt+wprojt (18.9MB cumulative). Attention over-reads <=300KB past
    // qkvb (absorbed by vt).
    unsigned short* p = (unsigned short*)d_ws;
    unsigned short* xb     = p;
    unsigned short* ao     = p; p += (size_t)NROWS * 768;
    unsigned short* wqkvt  = p; p += (size_t)QKVC * 768;
    unsigned short* wprojt = p; p += (size_t)768 * 768;
    unsigned short* qkvb   = p; p += (size_t)NROWS * QKVC;
    unsigned short* vt     = p; p += (size_t)NBATCH * NHEAD * 64 * NPAD;

    int mT = (NROWS + 127) / 128;   // 73
    int mG = (mT + 7) / 8;          // 10 groups of 8 m-tiles (XCD stripes)

    k_convert_x<<<(NROWS * 768 / 4) / 256, 256, 0, stream>>>(x, xb);
    k_transpose_w<<<dim3(QKVC / 64, 768 / 64), 256, 0, stream>>>(Wqkv, wqkvt, 768, QKVC);
    k_transpose_w<<<dim3(768 / 64, 768 / 64), 256, 0, stream>>>(Wproj, wprojt, 768, 768);
    k_gemm<false><<<mG * 8 * (QKVC / 128), 256, 0, stream>>>(
        xb, wqkvt, bqkv, (void*)qkvb, QKVC);
    k_vtrans<<<dim3(NPAD / 64, NHEAD, NBATCH), 256, 0, stream>>>(qkvb, vt);
    k_attn<<<dim3(NPAD / 128, NHEAD, NBATCH), 256, 0, stream>>>(qkvb, vt, policy, ao);
    k_gemm<true><<<mG * 8 * (768 / 128), 256, 0, stream>>>(
        ao, wprojt, bproj, (void*)out, 768);
}